// Round 1
// baseline (143.950 us; speedup 1.0000x reference)
//
#include <hip/hip_runtime.h>

// Problem constants (from reference)
#define BB      2
#define CC      256
#define HH      384
#define WW      384
#define N_ACT   16384
#define GRID_N  192                 // index grid; coord = 2*idx (OFFSET=0, STRIDE=2)
#define PLANE_F4 ((HH * WW) / 4)    // 36864 float4 per (b,c) plane
#define ROW_F4   (WW / 4)           // 96 float4 per row

// --- Kernel 1: init winner map to -1 ---------------------------------------
__global__ void init_winner_kernel(int* __restrict__ winner) {
    int i = blockIdx.x * blockDim.x + threadIdx.x;
    if (i < GRID_N * GRID_N) winner[i] = -1;
}

// --- Kernel 2: winner[cell] = max k writing to that cell (numpy last-wins) --
__global__ void winner_scatter_kernel(const int* __restrict__ idx,
                                      int* __restrict__ winner) {
    int k = blockIdx.x * blockDim.x + threadIdx.x;
    if (k < N_ACT) {
        int iy = idx[2 * k];
        int ix = idx[2 * k + 1];
        atomicMax(&winner[iy * GRID_N + ix], k);
    }
}

// --- Kernel 3: fused copy + scatter-resolve ---------------------------------
// Grid: (PLANE_F4/256, B*C) ; one thread per output float4.
__global__ void scatter_main_kernel(const float4* __restrict__ orig,
                                    const float* __restrict__ x,
                                    const int* __restrict__ winner,
                                    float4* __restrict__ out) {
    int bc  = blockIdx.y;                                    // 0..511
    int rem = blockIdx.x * blockDim.x + threadIdx.x;         // 0..36863
    long long base = (long long)bc * PLANE_F4 + rem;

    float4 v = orig[base];

    int y  = rem / ROW_F4;            // row within plane
    int x4 = rem - y * ROW_F4;        // float4 column; covers x = 4*x4 .. 4*x4+3

    if ((y & 1) == 0) {               // only even rows contain active sites
        int gy = y >> 1;
        int gx = x4 << 1;             // grid col of x=4*x4 ; gx+1 is that of x=4*x4+2
        const int* wrow = winner + gy * GRID_N;
        int w0 = wrow[gx];
        int w1 = wrow[gx + 1];
        const float* xp = x + (long long)bc * N_ACT;
        if (w0 >= 0) v.x = xp[w0];
        if (w1 >= 0) v.z = xp[w1];
    }

    out[base] = v;
}

extern "C" void kernel_launch(void* const* d_in, const int* in_sizes, int n_in,
                              void* d_out, int out_size, void* d_ws, size_t ws_size,
                              hipStream_t stream) {
    const float* x    = (const float*)d_in[0];   // [B, C, N_ACT]
    const float* orig = (const float*)d_in[1];   // [B, C, H, W]
    const int*   idx  = (const int*)d_in[2];     // [N_ACT, 2]
    float*       out  = (float*)d_out;           // [B, C, H, W]
    int*         winner = (int*)d_ws;            // GRID_N*GRID_N ints = 147456 B

    // 1. winner map = -1
    init_winner_kernel<<<dim3((GRID_N * GRID_N + 255) / 256), dim3(256), 0, stream>>>(winner);
    // 2. last-write-wins resolution via atomicMax over k
    winner_scatter_kernel<<<dim3((N_ACT + 255) / 256), dim3(256), 0, stream>>>(idx, winner);
    // 3. fused copy + patch
    scatter_main_kernel<<<dim3(PLANE_F4 / 256, BB * CC), dim3(256), 0, stream>>>(
        (const float4*)orig, x, winner, (float4*)out);
}

// Round 3
// 135.742 us; speedup vs baseline: 1.0605x; 1.0605x over previous
//
#include <hip/hip_runtime.h>

// Problem constants (from reference)
#define BB      2
#define CC      256
#define HH      384
#define WW      384
#define N_ACT   16384
#define GRID_N  192                 // index grid; coord = 2*idx (OFFSET=0, STRIDE=2)
#define PLANE_F4 ((HH * WW) / 4)    // 36864 float4 per (b,c) plane
#define ROW_F4   (WW / 4)           // 96 float4 per row
#define PAIRS_PER_PLANE (PLANE_F4 / 2)   // 18432 row-pair float4 slots

// Native clang vector type — required by __builtin_nontemporal_load/store.
typedef float  fx4 __attribute__((ext_vector_type(4)));

// --- Kernel 1: winner[cell] = max k writing to that cell (numpy last-wins) --
__global__ void winner_scatter_kernel(const int* __restrict__ idx,
                                      int* __restrict__ winner) {
    int k = blockIdx.x * blockDim.x + threadIdx.x;
    if (k < N_ACT) {
        int iy = idx[2 * k];
        int ix = idx[2 * k + 1];
        atomicMax(&winner[iy * GRID_N + ix], k);
    }
}

// --- Kernel 2: fused copy + scatter-resolve, one thread per row-pair float4 -
// Grid: (PAIRS_PER_PLANE/256, B*C). Thread handles float4 at (2*gy, col) and
// (2*gy+1, col) of its plane. Only the even row can contain active sites
// (lanes [0] at x=4*col and [2] at x=4*col+2).
__global__ void scatter_main_kernel(const fx4* __restrict__ orig,
                                    const float* __restrict__ x,
                                    const int* __restrict__ winner,
                                    fx4* __restrict__ out) {
    int bc = blockIdx.y;                                   // 0..511
    int q  = blockIdx.x * blockDim.x + threadIdx.x;        // 0..18431
    int gy  = q / ROW_F4;                                  // grid row 0..191
    int col = q - gy * ROW_F4;                             // float4 col 0..95

    int base = bc * PLANE_F4 + (gy * 2) * ROW_F4 + col;    // even row slot

    // Issue both stream loads + the winner load up front (independent).
    fx4 ve = __builtin_nontemporal_load(&orig[base]);
    fx4 vo = __builtin_nontemporal_load(&orig[base + ROW_F4]);
    const int2* wrow2 = reinterpret_cast<const int2*>(winner + gy * GRID_N);
    int2 w = wrow2[col];                                   // cells gx=2col, 2col+1

    if (w.x >= 0 || w.y >= 0) {
        const float* xp = x + bc * N_ACT;
        if (w.x >= 0) ve[0] = xp[w.x];
        if (w.y >= 0) ve[2] = xp[w.y];
    }

    __builtin_nontemporal_store(ve, &out[base]);
    __builtin_nontemporal_store(vo, &out[base + ROW_F4]);
}

extern "C" void kernel_launch(void* const* d_in, const int* in_sizes, int n_in,
                              void* d_out, int out_size, void* d_ws, size_t ws_size,
                              hipStream_t stream) {
    const float* x    = (const float*)d_in[0];   // [B, C, N_ACT]
    const float* orig = (const float*)d_in[1];   // [B, C, H, W]
    const int*   idx  = (const int*)d_in[2];     // [N_ACT, 2]
    float*       out  = (float*)d_out;           // [B, C, H, W]
    int*         winner = (int*)d_ws;            // GRID_N*GRID_N ints = 147456 B

    // 1. winner map = -1 (0xFF bytes) — async memset is graph-capturable
    (void)hipMemsetAsync(winner, 0xFF, GRID_N * GRID_N * sizeof(int), stream);
    // 2. last-write-wins resolution via atomicMax over k
    winner_scatter_kernel<<<dim3((N_ACT + 255) / 256), dim3(256), 0, stream>>>(idx, winner);
    // 3. fused copy + patch, row-pair threads
    scatter_main_kernel<<<dim3(PAIRS_PER_PLANE / 256, BB * CC), dim3(256), 0, stream>>>(
        (const fx4*)orig, x, winner, (fx4*)out);
}